// Round 13
// baseline (2206.823 us; speedup 1.0000x reference)
//
#include <hip/hip_runtime.h>
#include <hip/hip_bf16.h>

#define N_ATOMS 100000
#define N_EDGES 1600000
#define D       128
#define DE      100
#define DSPH    9

typedef __hip_bfloat16 bf16;
typedef unsigned short ushort_t;
typedef short s16x8 __attribute__((ext_vector_type(8)));   // 8 bf16 (4 VGPR)
typedef float f32x4 __attribute__((ext_vector_type(4)));   // MFMA acc

#define MFMA16(a, b, c) __builtin_amdgcn_mfma_f32_16x16x32_bf16(a, b, c, 0, 0, 0)

__device__ __forceinline__ float blo(unsigned int u) {
  union { unsigned int i; float f; } v; v.i = u << 16; return v.f;
}
__device__ __forceinline__ float bhi(unsigned int u) {
  union { unsigned int i; float f; } v; v.i = u & 0xffff0000u; return v.f;
}
__device__ __forceinline__ unsigned short f2b(float x) {
  bf16 h = __float2bfloat16(x);
  return *(unsigned short*)&h;
}
__device__ __forceinline__ float fsig(float x) {
  return __builtin_amdgcn_rcpf(1.0f + __expf(-x));
}
__device__ __forceinline__ float fsilu(float x) { return x * fsig(x); }

// ---------------------------------------------------------------------------
// k_wprepall: fused weight-fragment prep (k_tile's WF + k_tabmm's WF2).
// ---------------------------------------------------------------------------
__global__ __launch_bounds__(256) void k_wprepall(
    const float* __restrict__ W1, const float* __restrict__ b1,
    const float* __restrict__ W2, const float* __restrict__ W3,
    const float* __restrict__ G1, const float* __restrict__ g1v,
    const float* __restrict__ G2, const float* __restrict__ G3,
    ushort_t* __restrict__ WF, ushort_t* __restrict__ WF2)
{
  const int tid = threadIdx.x;
  const int lane = tid & 63, w = tid >> 6, fr = lane & 15, fg = lane >> 4;
  s16x8 fb[20];
#pragma unroll
  for (int q = 0; q < 2; ++q) {
    const int j = 16 * (2 * w + q) + fr;
    s16x8 bm, bg;
#pragma unroll
    for (int kk = 0; kk < 8; ++kk) {
      const int k = 8 * fg + kk;
      short vm = 0, vg = 0;
      if (k < 9)        { vm = (short)f2b(W1[(256 + k) * 128 + j]); vg = (short)f2b(G1[(256 + k) * 128 + j]); }
      else if (k == 31) { vm = (short)f2b(b1[j]);                    vg = (short)f2b(g1v[j]); }
      bm[kk] = vm; bg[kk] = vg;
    }
    fb[0 + q] = bm; fb[2 + q] = bg;
  }
  {
    const int j = 16 * w + fr;
#pragma unroll
    for (int ks = 0; ks < 4; ++ks) {
      s16x8 bm, bg;
#pragma unroll
      for (int kk = 0; kk < 8; ++kk) {
        const int k = 32 * ks + 8 * fg + kk;
        bm[kk] = (short)f2b(W2[k * 64 + j]);
        bg[kk] = (short)f2b(G2[k * 64 + j]);
      }
      fb[4 + ks] = bm; fb[8 + ks] = bg;
    }
  }
#pragma unroll
  for (int q = 0; q < 2; ++q) {
    const int j = 16 * (2 * w + q) + fr;
#pragma unroll
    for (int ks = 0; ks < 2; ++ks) {
      s16x8 bm, bg;
#pragma unroll
      for (int kk = 0; kk < 8; ++kk) {
        const int k = 32 * ks + 8 * fg + kk;
        bm[kk] = (short)f2b(W3[k * 128 + j]);
        bg[kk] = (short)f2b(G3[k * 128 + j]);
      }
      fb[12 + 2 * q + ks] = bm; fb[16 + 2 * q + ks] = bg;
    }
  }
#pragma unroll
  for (int f = 0; f < 20; ++f)
    ((s16x8*)WF)[f * 256 + tid] = fb[f];

  const int side = w >> 1, jbase = 64 * (w & 1);
  s16x8* WF2v = (s16x8*)WF2;
#pragma unroll
  for (int ks = 0; ks < 4; ++ks)
#pragma unroll
    for (int cf = 0; cf < 4; ++cf) {
      s16x8 bm, bg;
#pragma unroll
      for (int kk = 0; kk < 8; ++kk) {
        const int k = 32 * ks + 8 * fg + kk;
        const int j = jbase + 16 * cf + fr;
        const int row = side ? (128 + k) : k;
        bm[kk] = (short)f2b(W1[row * 128 + j]);
        bg[kk] = (short)f2b(G1[row * 128 + j]);
      }
      WF2v[((w * 4 + ks) * 8 + cf) * 64 + lane] = bm;
      WF2v[((w * 4 + ks) * 8 + cf + 4) * 64 + lane] = bg;
    }
}

// ---------------------------------------------------------------------------
// k_tabmm: MFMA GEMM -> packed tables T_A = PA|PGA<<16, T_B = PB|PGB<<16.
// Also writes out = atom_attr (residual base) while staging.
// ---------------------------------------------------------------------------
__global__ __launch_bounds__(256, 2) void k_tabmm(
    const float* __restrict__ atom, const ushort_t* __restrict__ WF2,
    unsigned* __restrict__ T_A, unsigned* __restrict__ T_B,
    float* __restrict__ out)
{
  __shared__ __align__(16) char ALDS[16384];   // 64 rows x 128 bf16 (swz16)
  const int tid = threadIdx.x;
  const int lane = tid & 63, w = tid >> 6, fr = lane & 15, fg = lane >> 4;
  const int abase = blockIdx.x * 64;

  for (int i = tid; i < 2048; i += 256) {
    const int row = i >> 5, c4 = i & 31;
    const int a = abase + row;
    float4 v = make_float4(0.f, 0.f, 0.f, 0.f);
    if (a < N_ATOMS) {
      v = *(const float4*)(atom + (size_t)a * D + 4 * c4);
      *(float4*)(out + (size_t)a * D + 4 * c4) = v;
    }
    const unsigned lo = (unsigned)f2b(v.x) | ((unsigned)f2b(v.y) << 16);
    const unsigned hi = (unsigned)f2b(v.z) | ((unsigned)f2b(v.w) << 16);
    const int byte = row * 256 + ((8 * c4) ^ ((row & 15) << 4));
    *(uint2*)(ALDS + byte) = make_uint2(lo, hi);
  }
  __syncthreads();

  f32x4 am[4][4], ag[4][4];
#pragma unroll
  for (int rf = 0; rf < 4; ++rf)
#pragma unroll
    for (int cf = 0; cf < 4; ++cf) {
      am[rf][cf] = (f32x4){0.f, 0.f, 0.f, 0.f};
      ag[rf][cf] = (f32x4){0.f, 0.f, 0.f, 0.f};
    }

  const s16x8* WF2v = (const s16x8*)WF2;
#pragma unroll
  for (int ks = 0; ks < 4; ++ks) {
    s16x8 a[4];
#pragma unroll
    for (int rf = 0; rf < 4; ++rf) {
      const int row = 16 * rf + fr;
      a[rf] = *(const s16x8*)(ALDS + row * 256 + ((64 * ks + 16 * fg) ^ (fr << 4)));
    }
#pragma unroll
    for (int cf = 0; cf < 4; ++cf) {
      const s16x8 Bm = WF2v[((w * 4 + ks) * 8 + cf) * 64 + lane];
      const s16x8 Bg = WF2v[((w * 4 + ks) * 8 + cf + 4) * 64 + lane];
#pragma unroll
      for (int rf = 0; rf < 4; ++rf) {
        am[rf][cf] = MFMA16(a[rf], Bm, am[rf][cf]);
        ag[rf][cf] = MFMA16(a[rf], Bg, ag[rf][cf]);
      }
    }
  }

  const int side = w >> 1, jbase = 64 * (w & 1);
  unsigned* T = side ? T_B : T_A;
#pragma unroll
  for (int rf = 0; rf < 4; ++rf)
#pragma unroll
    for (int cf = 0; cf < 4; ++cf)
#pragma unroll
      for (int r = 0; r < 4; ++r) {
        const int a = abase + 16 * rf + 4 * fg + r;
        if (a < N_ATOMS) {
          const unsigned u = (unsigned)f2b(am[rf][cf][r]) |
                             ((unsigned)f2b(ag[rf][cf][r]) << 16);
          T[(size_t)a * D + jbase + 16 * cf + fr] = u;
        }
      }
}

// ---------------------------------------------------------------------------
// k_sc_hist: sc[e] = ea[e,:]@We + be (8 lanes/edge) + dst histogram.
// ---------------------------------------------------------------------------
__global__ __launch_bounds__(256) void k_sc_hist(const float* __restrict__ ea,
                                                 const float* __restrict__ We,
                                                 const float* __restrict__ be,
                                                 const int* __restrict__ ei,
                                                 float* __restrict__ sc,
                                                 int* __restrict__ counts) {
  const int tid = threadIdx.x;
  const int r = tid & 7;
  const long e = (long)blockIdx.x * 32 + (tid >> 3);
  const float4* row = (const float4*)(ea + e * DE);
  const float4* Wv = (const float4*)We;
  const float4 w0 = Wv[r], w1 = Wv[r + 8], w2 = Wv[r + 16];
  const float4 d0 = row[r], d1 = row[r + 8], d2 = row[r + 16];
  float s = d0.x * w0.x;
  s = fmaf(d0.y, w0.y, s); s = fmaf(d0.z, w0.z, s); s = fmaf(d0.w, w0.w, s);
  s = fmaf(d1.x, w1.x, s); s = fmaf(d1.y, w1.y, s); s = fmaf(d1.z, w1.z, s);
  s = fmaf(d1.w, w1.w, s); s = fmaf(d2.x, w2.x, s); s = fmaf(d2.y, w2.y, s);
  s = fmaf(d2.z, w2.z, s); s = fmaf(d2.w, w2.w, s);
  if (r == 0) {
    const float4 w3 = Wv[24], d3 = row[24];
    s = fmaf(d3.x, w3.x, s); s = fmaf(d3.y, w3.y, s);
    s = fmaf(d3.z, w3.z, s); s = fmaf(d3.w, w3.w, s);
  }
  s += __shfl_xor(s, 1); s += __shfl_xor(s, 2); s += __shfl_xor(s, 4);
  if (r == 0) {
    sc[e] = s + be[0];
    atomicAdd(&counts[ei[N_EDGES + e]], 1);
  }
}

// ---------------------------------------------------------------------------
// CSR: scan + scatter (R9 form: memset-initialized cursor, scatter reads roff
// — keeps cursor lines clean/distributed across XCD L2s; R10's scan-side init
// parked them dirty in one XCD and cost ~100us of atomic serialization)
// ---------------------------------------------------------------------------
__global__ __launch_bounds__(1024) void k_scan(const int* __restrict__ counts,
                                               int* __restrict__ roff) {
  __shared__ int ssum[1024];
  const int tid = threadIdx.x;
  const int CH = (N_ATOMS + 1023) / 1024;
  const int base = tid * CH;
  int s = 0;
  for (int k = 0; k < CH; ++k) {
    int idx = base + k;
    if (idx < N_ATOMS) s += counts[idx];
  }
  ssum[tid] = s;
  __syncthreads();
  for (int off = 1; off < 1024; off <<= 1) {
    int v = 0;
    if (tid >= off) v = ssum[tid - off];
    __syncthreads();
    if (tid >= off) ssum[tid] += v;
    __syncthreads();
  }
  s = (tid == 0) ? 0 : ssum[tid - 1];
  for (int k = 0; k < CH; ++k) {
    int idx = base + k;
    if (idx < N_ATOMS) { roff[idx] = s; s += counts[idx]; }
  }
  if (tid == 1023) roff[N_ATOMS] = s;
}

__global__ __launch_bounds__(256) void k_scatter(const int* __restrict__ ei,
                                                 const int* __restrict__ roff,
                                                 int* __restrict__ cursor,
                                                 int* __restrict__ perm) {
  int e = blockIdx.x * 256 + threadIdx.x;
  if (e < N_EDGES) {
    int d = ei[N_EDGES + e];
    int p = atomicAdd(&cursor[d], 1);
    perm[roff[d] + p] = e;
  }
}

// ---------------------------------------------------------------------------
// k_tile: R13 — 2 tiles of 64 dst-sorted edges per block (grid 12500),
// 256 thr (4 waves), 3 blocks/CU. All 20 weight frags + biases hoisted
// outside the tile loop (loaded once per block, amortized over 2 tiles).
// Async-split gather order (R9) retained inside the loop.
// LDS overlay (50176 B): X [0,32K) H1 -> MSG; Y [32K,48K) sph -> H2; tails.
// ---------------------------------------------------------------------------
#define OFF_H1M 0
#define OFF_H1G 16384
#define OFF_MSG 0
#define OFF_SPH 32768
#define OFF_H2M 32768
#define OFF_H2G 40960
#define OFF_DST 49152
#define OFF_SC  49408
#define OFF_SRC 49664
#define OFF_E   49920

__global__ __launch_bounds__(256, 3) void k_tile(
    const float* __restrict__ eap,
    const int*  __restrict__ ei, const int* __restrict__ perm,
    const unsigned* __restrict__ T_A, const unsigned* __restrict__ T_B,
    const ushort_t* __restrict__ WF,
    const float* __restrict__ b2v, const float* __restrict__ g2v,
    const float* __restrict__ b3v, const float* __restrict__ g3v,
    const float* __restrict__ sc_all,
    float* __restrict__ out)
{
  __shared__ __align__(16) char BUF[50176];
  const int tid  = threadIdx.x;
  const int lane = tid & 63;
  const int w    = tid >> 6;        // wave 0..3
  const int fr   = lane & 15;       // frag row
  const int fg   = lane >> 4;       // frag k-group / C row-group

  int*   e_s   = (int*)(BUF + OFF_E);
  int*   src_s = (int*)(BUF + OFF_SRC);
  int*   dst_s = (int*)(BUF + OFF_DST);
  float* sc_s  = (float*)(BUF + OFF_SC);

  // ---- block prologue: ALL weight fragments + biases (once per block) ----
  const s16x8* WFv = (const s16x8*)WF;
  s16x8 B1m[2], B1g[2], B2m[4], B2g[4], B3m[2][2], B3g[2][2];
#pragma unroll
  for (int q = 0; q < 2; ++q) { B1m[q] = WFv[(0 + q) * 256 + tid]; B1g[q] = WFv[(2 + q) * 256 + tid]; }
#pragma unroll
  for (int ks = 0; ks < 4; ++ks) { B2m[ks] = WFv[(4 + ks) * 256 + tid]; B2g[ks] = WFv[(8 + ks) * 256 + tid]; }
#pragma unroll
  for (int q = 0; q < 2; ++q)
#pragma unroll
    for (int ks = 0; ks < 2; ++ks) {
      B3m[q][ks] = WFv[(12 + 2 * q + ks) * 256 + tid];
      B3g[q][ks] = WFv[(16 + 2 * q + ks) * 256 + tid];
    }
  const float b2j = b2v[16 * w + fr], g2j = g2v[16 * w + fr];
  const float b3j0 = b3v[16 * 2 * w + fr],       g3j0 = g3v[16 * 2 * w + fr];
  const float b3j1 = b3v[16 * (2 * w + 1) + fr], g3j1 = g3v[16 * (2 * w + 1) + fr];

  for (int it = 0; it < 2; ++it) {
    const long E0 = ((long)blockIdx.x * 2 + it) * 64;

    // ---- phase 1: edge indices + scalar + sph pad (k>=10; k31 = bias 1.0) ----
    if (tid < 64) {
      const int e = perm[E0 + tid];
      e_s[tid]   = e;
      src_s[tid] = ei[e];
      dst_s[tid] = ei[N_EDGES + e];
      sc_s[tid]  = sc_all[e];
    }
    for (int idx = tid; idx < 64 * 11; idx += 256) {
      const int i = idx / 11, ww = 5 + idx % 11;
      ((unsigned int*)(BUF + OFF_SPH))[i * 16 + ww] = (ww == 15) ? 0x3F800000u : 0u;
    }
    __syncthreads();   // bar A: e_s/src/dst/sc + sph pad visible

    // ---- phase 2a: eap loads into regs (issued FIRST) ----
    float sp[9];
    if (tid < 64) {
      const float* p = eap + (size_t)e_s[tid] * DSPH;
#pragma unroll
      for (int k = 0; k < 9; ++k) sp[k] = p[k];
    }

    // ---- phase 2b: hoisted T_A/T_B gathers (64 u32 loads, in flight) ----
    unsigned va_r[4][2][4], vb_r[4][2][4];
#pragma unroll
    for (int me = 0; me < 4; ++me)
#pragma unroll
      for (int q = 0; q < 2; ++q) {
        const int col = 16 * (2 * w + q) + fr;
#pragma unroll
        for (int r = 0; r < 4; ++r) {
          const int e = 16 * me + 4 * fg + r;
          va_r[me][q][r] = T_A[(size_t)src_s[e] * D + col];
          vb_r[me][q][r] = T_B[(size_t)dst_s[e] * D + col];
        }
      }

    // ---- phase 2c: sph writes (waits only on eap loads) ----
    if (tid < 64) {
#pragma unroll
      for (int k = 0; k < 9; ++k)
        *(unsigned short*)(BUF + OFF_SPH + tid * 64 + k * 2) = f2b(sp[k]);
    }
    __syncthreads();   // bar B: sph visible

    // ---- L1: Z1 = sph @ W1cT(+bias) ----
    f32x4 a1m[4][2], a1g[4][2];
#pragma unroll
    for (int me = 0; me < 4; ++me)
#pragma unroll
      for (int q = 0; q < 2; ++q) { a1m[me][q] = (f32x4){0.f,0.f,0.f,0.f}; a1g[me][q] = (f32x4){0.f,0.f,0.f,0.f}; }
#pragma unroll
    for (int me = 0; me < 4; ++me) {
      const s16x8 a = *(const s16x8*)(BUF + OFF_SPH + (16 * me + fr) * 64 + fg * 16);
#pragma unroll
      for (int q = 0; q < 2; ++q) {
        a1m[me][q] = MFMA16(a, B1m[q], a1m[me][q]);
        a1g[me][q] = MFMA16(a, B1g[q], a1g[me][q]);
      }
    }
    // ---- L1 epi: add gathered pair-sums (already in regs), silu -> H1 ----
#pragma unroll
    for (int me = 0; me < 4; ++me)
#pragma unroll
      for (int q = 0; q < 2; ++q) {
        const int col = 16 * (2 * w + q) + fr;
#pragma unroll
        for (int r = 0; r < 4; ++r) {
          const int e = 16 * me + 4 * fg + r;
          const unsigned va = va_r[me][q][r];
          const unsigned vb = vb_r[me][q][r];
          const float zm = a1m[me][q][r] + blo(va) + blo(vb);
          const float zg = a1g[me][q][r] + bhi(va) + bhi(vb);
          const int cb = (col * 2) ^ ((e & 15) << 4);
          *(unsigned short*)(BUF + OFF_H1M + e * 256 + cb) = f2b(fsilu(zm));
          *(unsigned short*)(BUF + OFF_H1G + e * 256 + cb) = f2b(fsilu(zg));
        }
      }
    __syncthreads();   // bar C: H1 ready

    // ---- L2: Z2 = H1 @ W2 (+b2) ; silu -> H2 (Y region) ----
    f32x4 a2m[4], a2g[4];
#pragma unroll
    for (int me = 0; me < 4; ++me) { a2m[me] = (f32x4){b2j,b2j,b2j,b2j}; a2g[me] = (f32x4){g2j,g2j,g2j,g2j}; }
#pragma unroll
    for (int me = 0; me < 4; ++me) {
      const int row = 16 * me + fr;
#pragma unroll
      for (int ks = 0; ks < 4; ++ks) {
        const int cb = (64 * ks + 16 * fg) ^ ((row & 15) << 4);
        const s16x8 am = *(const s16x8*)(BUF + OFF_H1M + row * 256 + cb);
        const s16x8 ag = *(const s16x8*)(BUF + OFF_H1G + row * 256 + cb);
        a2m[me] = MFMA16(am, B2m[ks], a2m[me]);
        a2g[me] = MFMA16(ag, B2g[ks], a2g[me]);
      }
    }
    {
      const int j2 = 16 * w + fr;
#pragma unroll
      for (int me = 0; me < 4; ++me)
#pragma unroll
        for (int r = 0; r < 4; ++r) {
          const int e = 16 * me + 4 * fg + r;
          const int cb = (j2 * 2) ^ ((e & 7) << 4);
          *(unsigned short*)(BUF + OFF_H2M + e * 128 + cb) = f2b(fsilu(a2m[me][r]));
          *(unsigned short*)(BUF + OFF_H2G + e * 128 + cb) = f2b(fsilu(a2g[me][r]));
        }
    }
    __syncthreads();   // bar D: H2 ready (and all H1 reads done)

    // ---- L3: Z3 = H2 @ W3 (+b3) ; msg -> MSG (X region, overlays H1) ----
    f32x4 a3m[4][2], a3g[4][2];
#pragma unroll
    for (int me = 0; me < 4; ++me) {
      a3m[me][0] = (f32x4){b3j0,b3j0,b3j0,b3j0}; a3g[me][0] = (f32x4){g3j0,g3j0,g3j0,g3j0};
      a3m[me][1] = (f32x4){b3j1,b3j1,b3j1,b3j1}; a3g[me][1] = (f32x4){g3j1,g3j1,g3j1,g3j1};
    }
#pragma unroll
    for (int me = 0; me < 4; ++me) {
      const int row = 16 * me + fr;
#pragma unroll
      for (int ks = 0; ks < 2; ++ks) {
        const int cb = (64 * ks + 16 * fg) ^ ((row & 7) << 4);
        const s16x8 am = *(const s16x8*)(BUF + OFF_H2M + row * 128 + cb);
        const s16x8 ag = *(const s16x8*)(BUF + OFF_H2G + row * 128 + cb);
#pragma unroll
        for (int q = 0; q < 2; ++q) {
          a3m[me][q] = MFMA16(am, B3m[q][ks], a3m[me][q]);
          a3g[me][q] = MFMA16(ag, B3g[q][ks], a3g[me][q]);
        }
      }
    }
#pragma unroll
    for (int me = 0; me < 4; ++me)
#pragma unroll
      for (int q = 0; q < 2; ++q) {
        const int col = 16 * (2 * w + q) + fr;
#pragma unroll
        for (int r = 0; r < 4; ++r) {
          const int e = 16 * me + 4 * fg + r;
          const float msg = fsilu(a3m[me][q][r]) * fsig(a3g[me][q][r]) * sc_s[e];
          *(float*)(BUF + OFF_MSG + (e * 128 + col) * 4) = msg;
        }
      }
    __syncthreads();   // bar E: MSG ready

    // ---- segmented reduce: col-pair x edge-quarter (16-long chains) ----
    {
      const int cp = tid & 63;          // cols 2cp, 2cp+1
      const int qt = tid >> 6;          // quarter 0..3 (wave-uniform)
      const int base = 16 * qt;
      int cur = dst_s[base];
      float2 acc = *(const float2*)(BUF + OFF_MSG + (base * 128 + 2 * cp) * 4);
      for (int e2 = 1; e2 < 16; ++e2) {
        const int d = dst_s[base + e2];
        const float2 v = *(const float2*)(BUF + OFF_MSG + ((base + e2) * 128 + 2 * cp) * 4);
        if (d != cur) {
          atomicAdd(out + (size_t)cur * D + 2 * cp,     acc.x);
          atomicAdd(out + (size_t)cur * D + 2 * cp + 1, acc.y);
          cur = d; acc = v;
        } else { acc.x += v.x; acc.y += v.y; }
      }
      atomicAdd(out + (size_t)cur * D + 2 * cp,     acc.x);
      atomicAdd(out + (size_t)cur * D + 2 * cp + 1, acc.y);
    }
    __syncthreads();   // loop barrier: reduce reads done before next phase 1
  }
}

// ---------------------------------------------------------------------------
extern "C" void kernel_launch(void* const* d_in, const int* in_sizes, int n_in,
                              void* d_out, int out_size, void* d_ws, size_t ws_size,
                              hipStream_t stream) {
  const float* atom = (const float*)d_in[0];
  const float* ea   = (const float*)d_in[1];
  const float* eap  = (const float*)d_in[2];
  const int*   ei   = (const int*)d_in[3];
  const float* W1 = (const float*)d_in[5];
  const float* b1 = (const float*)d_in[6];
  const float* W2 = (const float*)d_in[7];
  const float* b2 = (const float*)d_in[8];
  const float* W3 = (const float*)d_in[9];
  const float* b3 = (const float*)d_in[10];
  const float* G1 = (const float*)d_in[11];
  const float* g1 = (const float*)d_in[12];
  const float* G2 = (const float*)d_in[13];
  const float* g2 = (const float*)d_in[14];
  const float* G3 = (const float*)d_in[15];
  const float* g3 = (const float*)d_in[16];
  const float* We = (const float*)d_in[17];
  const float* be = (const float*)d_in[18];
  float* out = (float*)d_out;

  char* wp = (char*)d_ws;
  unsigned* T_A = (unsigned*)wp;            wp += (size_t)N_ATOMS * D * 4;
  unsigned* T_B = (unsigned*)wp;            wp += (size_t)N_ATOMS * D * 4;
  int* counts = (int*)wp;                   wp += (size_t)N_ATOMS * 4;
  int* roff   = (int*)wp;                   wp += (size_t)(N_ATOMS + 4) * 4;
  int* cursor = (int*)wp;                   wp += (size_t)N_ATOMS * 4;
  int* perm   = (int*)wp;                   wp += (size_t)(N_EDGES + 64) * 4;
  ushort_t* WF  = (ushort_t*)wp;            wp += (size_t)20 * 256 * 8 * 2;
  ushort_t* WF2 = (ushort_t*)wp;            wp += (size_t)4 * 4 * 8 * 64 * 8 * 2;
  float* sc_all = (float*)wp;               wp += (size_t)N_EDGES * 4;

  hipMemsetAsync(counts, 0, (size_t)N_ATOMS * 4, stream);
  hipMemsetAsync(cursor, 0, (size_t)N_ATOMS * 4, stream);

  hipLaunchKernelGGL(k_wprepall, dim3(1), dim3(256), 0, stream,
                     W1, b1, W2, W3, G1, g1, G2, G3, WF, WF2);
  hipLaunchKernelGGL(k_sc_hist, dim3(N_EDGES / 32), dim3(256), 0, stream,
                     ea, We, be, ei, sc_all, counts);
  hipLaunchKernelGGL(k_scan, dim3(1), dim3(1024), 0, stream, counts, roff);
  hipLaunchKernelGGL(k_scatter, dim3((N_EDGES + 255) / 256), dim3(256), 0, stream,
                     ei, roff, cursor, perm);
  hipLaunchKernelGGL(k_tabmm, dim3((N_ATOMS + 63) / 64), dim3(256), 0, stream,
                     atom, WF2, T_A, T_B, out);
  hipLaunchKernelGGL(k_tile, dim3(N_EDGES / 128), dim3(256), 0, stream,
                     eap, ei, perm, T_A, T_B, WF, b2, g2, b3, g3, sc_all, out);
}

// Round 14
// 1173.108 us; speedup vs baseline: 1.8812x; 1.8812x over previous
//
#include <hip/hip_runtime.h>
#include <hip/hip_bf16.h>

#define N_ATOMS 100000
#define N_EDGES 1600000
#define D       128
#define DE      100
#define DSPH    9

typedef __hip_bfloat16 bf16;
typedef unsigned short ushort_t;
typedef short s16x8 __attribute__((ext_vector_type(8)));   // 8 bf16 (4 VGPR)
typedef float f32x4 __attribute__((ext_vector_type(4)));   // MFMA acc

#define MFMA16(a, b, c) __builtin_amdgcn_mfma_f32_16x16x32_bf16(a, b, c, 0, 0, 0)

__device__ __forceinline__ float blo(unsigned int u) {
  union { unsigned int i; float f; } v; v.i = u << 16; return v.f;
}
__device__ __forceinline__ float bhi(unsigned int u) {
  union { unsigned int i; float f; } v; v.i = u & 0xffff0000u; return v.f;
}
__device__ __forceinline__ unsigned short f2b(float x) {
  bf16 h = __float2bfloat16(x);
  return *(unsigned short*)&h;
}
__device__ __forceinline__ float fsig(float x) {
  return __builtin_amdgcn_rcpf(1.0f + __expf(-x));
}
__device__ __forceinline__ float fsilu(float x) { return x * fsig(x); }

// ---------------------------------------------------------------------------
// k_wprepall: fused weight-fragment prep (k_tile's WF + k_tabmm's WF2).
// ---------------------------------------------------------------------------
__global__ __launch_bounds__(256) void k_wprepall(
    const float* __restrict__ W1, const float* __restrict__ b1,
    const float* __restrict__ W2, const float* __restrict__ W3,
    const float* __restrict__ G1, const float* __restrict__ g1v,
    const float* __restrict__ G2, const float* __restrict__ G3,
    ushort_t* __restrict__ WF, ushort_t* __restrict__ WF2)
{
  const int tid = threadIdx.x;
  const int lane = tid & 63, w = tid >> 6, fr = lane & 15, fg = lane >> 4;
  s16x8 fb[20];
#pragma unroll
  for (int q = 0; q < 2; ++q) {
    const int j = 16 * (2 * w + q) + fr;
    s16x8 bm, bg;
#pragma unroll
    for (int kk = 0; kk < 8; ++kk) {
      const int k = 8 * fg + kk;
      short vm = 0, vg = 0;
      if (k < 9)        { vm = (short)f2b(W1[(256 + k) * 128 + j]); vg = (short)f2b(G1[(256 + k) * 128 + j]); }
      else if (k == 31) { vm = (short)f2b(b1[j]);                    vg = (short)f2b(g1v[j]); }
      bm[kk] = vm; bg[kk] = vg;
    }
    fb[0 + q] = bm; fb[2 + q] = bg;
  }
  {
    const int j = 16 * w + fr;
#pragma unroll
    for (int ks = 0; ks < 4; ++ks) {
      s16x8 bm, bg;
#pragma unroll
      for (int kk = 0; kk < 8; ++kk) {
        const int k = 32 * ks + 8 * fg + kk;
        bm[kk] = (short)f2b(W2[k * 64 + j]);
        bg[kk] = (short)f2b(G2[k * 64 + j]);
      }
      fb[4 + ks] = bm; fb[8 + ks] = bg;
    }
  }
#pragma unroll
  for (int q = 0; q < 2; ++q) {
    const int j = 16 * (2 * w + q) + fr;
#pragma unroll
    for (int ks = 0; ks < 2; ++ks) {
      s16x8 bm, bg;
#pragma unroll
      for (int kk = 0; kk < 8; ++kk) {
        const int k = 32 * ks + 8 * fg + kk;
        bm[kk] = (short)f2b(W3[k * 128 + j]);
        bg[kk] = (short)f2b(G3[k * 128 + j]);
      }
      fb[12 + 2 * q + ks] = bm; fb[16 + 2 * q + ks] = bg;
    }
  }
#pragma unroll
  for (int f = 0; f < 20; ++f)
    ((s16x8*)WF)[f * 256 + tid] = fb[f];

  const int side = w >> 1, jbase = 64 * (w & 1);
  s16x8* WF2v = (s16x8*)WF2;
#pragma unroll
  for (int ks = 0; ks < 4; ++ks)
#pragma unroll
    for (int cf = 0; cf < 4; ++cf) {
      s16x8 bm, bg;
#pragma unroll
      for (int kk = 0; kk < 8; ++kk) {
        const int k = 32 * ks + 8 * fg + kk;
        const int j = jbase + 16 * cf + fr;
        const int row = side ? (128 + k) : k;
        bm[kk] = (short)f2b(W1[row * 128 + j]);
        bg[kk] = (short)f2b(G1[row * 128 + j]);
      }
      WF2v[((w * 4 + ks) * 8 + cf) * 64 + lane] = bm;
      WF2v[((w * 4 + ks) * 8 + cf + 4) * 64 + lane] = bg;
    }
}

// ---------------------------------------------------------------------------
// k_tabmm: MFMA GEMM -> packed tables T_A = PA|PGA<<16, T_B = PB|PGB<<16.
// Also writes out = atom_attr (residual base) while staging.
// ---------------------------------------------------------------------------
__global__ __launch_bounds__(256, 2) void k_tabmm(
    const float* __restrict__ atom, const ushort_t* __restrict__ WF2,
    unsigned* __restrict__ T_A, unsigned* __restrict__ T_B,
    float* __restrict__ out)
{
  __shared__ __align__(16) char ALDS[16384];   // 64 rows x 128 bf16 (swz16)
  const int tid = threadIdx.x;
  const int lane = tid & 63, w = tid >> 6, fr = lane & 15, fg = lane >> 4;
  const int abase = blockIdx.x * 64;

  for (int i = tid; i < 2048; i += 256) {
    const int row = i >> 5, c4 = i & 31;
    const int a = abase + row;
    float4 v = make_float4(0.f, 0.f, 0.f, 0.f);
    if (a < N_ATOMS) {
      v = *(const float4*)(atom + (size_t)a * D + 4 * c4);
      *(float4*)(out + (size_t)a * D + 4 * c4) = v;
    }
    const unsigned lo = (unsigned)f2b(v.x) | ((unsigned)f2b(v.y) << 16);
    const unsigned hi = (unsigned)f2b(v.z) | ((unsigned)f2b(v.w) << 16);
    const int byte = row * 256 + ((8 * c4) ^ ((row & 15) << 4));
    *(uint2*)(ALDS + byte) = make_uint2(lo, hi);
  }
  __syncthreads();

  f32x4 am[4][4], ag[4][4];
#pragma unroll
  for (int rf = 0; rf < 4; ++rf)
#pragma unroll
    for (int cf = 0; cf < 4; ++cf) {
      am[rf][cf] = (f32x4){0.f, 0.f, 0.f, 0.f};
      ag[rf][cf] = (f32x4){0.f, 0.f, 0.f, 0.f};
    }

  const s16x8* WF2v = (const s16x8*)WF2;
#pragma unroll
  for (int ks = 0; ks < 4; ++ks) {
    s16x8 a[4];
#pragma unroll
    for (int rf = 0; rf < 4; ++rf) {
      const int row = 16 * rf + fr;
      a[rf] = *(const s16x8*)(ALDS + row * 256 + ((64 * ks + 16 * fg) ^ (fr << 4)));
    }
#pragma unroll
    for (int cf = 0; cf < 4; ++cf) {
      const s16x8 Bm = WF2v[((w * 4 + ks) * 8 + cf) * 64 + lane];
      const s16x8 Bg = WF2v[((w * 4 + ks) * 8 + cf + 4) * 64 + lane];
#pragma unroll
      for (int rf = 0; rf < 4; ++rf) {
        am[rf][cf] = MFMA16(a[rf], Bm, am[rf][cf]);
        ag[rf][cf] = MFMA16(a[rf], Bg, ag[rf][cf]);
      }
    }
  }

  const int side = w >> 1, jbase = 64 * (w & 1);
  unsigned* T = side ? T_B : T_A;
#pragma unroll
  for (int rf = 0; rf < 4; ++rf)
#pragma unroll
    for (int cf = 0; cf < 4; ++cf)
#pragma unroll
      for (int r = 0; r < 4; ++r) {
        const int a = abase + 16 * rf + 4 * fg + r;
        if (a < N_ATOMS) {
          const unsigned u = (unsigned)f2b(am[rf][cf][r]) |
                             ((unsigned)f2b(ag[rf][cf][r]) << 16);
          T[(size_t)a * D + jbase + 16 * cf + fr] = u;
        }
      }
}

// ---------------------------------------------------------------------------
// k_sc_hist: sc[e] = ea[e,:]@We + be (8 lanes/edge) + dst histogram.
// ---------------------------------------------------------------------------
__global__ __launch_bounds__(256) void k_sc_hist(const float* __restrict__ ea,
                                                 const float* __restrict__ We,
                                                 const float* __restrict__ be,
                                                 const int* __restrict__ ei,
                                                 float* __restrict__ sc,
                                                 int* __restrict__ counts) {
  const int tid = threadIdx.x;
  const int r = tid & 7;
  const long e = (long)blockIdx.x * 32 + (tid >> 3);
  const float4* row = (const float4*)(ea + e * DE);
  const float4* Wv = (const float4*)We;
  const float4 w0 = Wv[r], w1 = Wv[r + 8], w2 = Wv[r + 16];
  const float4 d0 = row[r], d1 = row[r + 8], d2 = row[r + 16];
  float s = d0.x * w0.x;
  s = fmaf(d0.y, w0.y, s); s = fmaf(d0.z, w0.z, s); s = fmaf(d0.w, w0.w, s);
  s = fmaf(d1.x, w1.x, s); s = fmaf(d1.y, w1.y, s); s = fmaf(d1.z, w1.z, s);
  s = fmaf(d1.w, w1.w, s); s = fmaf(d2.x, w2.x, s); s = fmaf(d2.y, w2.y, s);
  s = fmaf(d2.z, w2.z, s); s = fmaf(d2.w, w2.w, s);
  if (r == 0) {
    const float4 w3 = Wv[24], d3 = row[24];
    s = fmaf(d3.x, w3.x, s); s = fmaf(d3.y, w3.y, s);
    s = fmaf(d3.z, w3.z, s); s = fmaf(d3.w, w3.w, s);
  }
  s += __shfl_xor(s, 1); s += __shfl_xor(s, 2); s += __shfl_xor(s, 4);
  if (r == 0) {
    sc[e] = s + be[0];
    atomicAdd(&counts[ei[N_EDGES + e]], 1);
  }
}

// ---------------------------------------------------------------------------
// CSR: scan + scatter (memset-initialized cursor; scatter reads roff)
// ---------------------------------------------------------------------------
__global__ __launch_bounds__(1024) void k_scan(const int* __restrict__ counts,
                                               int* __restrict__ roff) {
  __shared__ int ssum[1024];
  const int tid = threadIdx.x;
  const int CH = (N_ATOMS + 1023) / 1024;
  const int base = tid * CH;
  int s = 0;
  for (int k = 0; k < CH; ++k) {
    int idx = base + k;
    if (idx < N_ATOMS) s += counts[idx];
  }
  ssum[tid] = s;
  __syncthreads();
  for (int off = 1; off < 1024; off <<= 1) {
    int v = 0;
    if (tid >= off) v = ssum[tid - off];
    __syncthreads();
    if (tid >= off) ssum[tid] += v;
    __syncthreads();
  }
  s = (tid == 0) ? 0 : ssum[tid - 1];
  for (int k = 0; k < CH; ++k) {
    int idx = base + k;
    if (idx < N_ATOMS) { roff[idx] = s; s += counts[idx]; }
  }
  if (tid == 1023) roff[N_ATOMS] = s;
}

__global__ __launch_bounds__(256) void k_scatter(const int* __restrict__ ei,
                                                 const int* __restrict__ roff,
                                                 int* __restrict__ cursor,
                                                 int* __restrict__ perm) {
  int e = blockIdx.x * 256 + threadIdx.x;
  if (e < N_EDGES) {
    int d = ei[N_EDGES + e];
    int p = atomicAdd(&cursor[d], 1);
    perm[roff[d] + p] = e;
  }
}

// ---------------------------------------------------------------------------
// k_tile: 64 dst-sorted edges per block, 256 thr (4 waves), 3 blocks/CU.
// Async-split: after bar A issue (eap regs) -> (64 T-gathers into regs) ->
// (B2 frag loads); B3 frag loads after bar C. Single tile per block —
// R13's 2-tile loop spilled (weight frags live across loop + per-tile arrays
// exceed the N=3 register budget). This register footprint needs exactly
// one tile in flight.
// LDS overlay (50176 B): X [0,32K) H1 -> MSG; Y [32K,48K) sph -> H2; tails.
// ---------------------------------------------------------------------------
#define OFF_H1M 0
#define OFF_H1G 16384
#define OFF_MSG 0
#define OFF_SPH 32768
#define OFF_H2M 32768
#define OFF_H2G 40960
#define OFF_DST 49152
#define OFF_SC  49408
#define OFF_SRC 49664
#define OFF_E   49920

__global__ __launch_bounds__(256, 3) void k_tile(
    const float* __restrict__ eap,
    const int*  __restrict__ ei, const int* __restrict__ perm,
    const unsigned* __restrict__ T_A, const unsigned* __restrict__ T_B,
    const ushort_t* __restrict__ WF,
    const float* __restrict__ b2v, const float* __restrict__ g2v,
    const float* __restrict__ b3v, const float* __restrict__ g3v,
    const float* __restrict__ sc_all,
    float* __restrict__ out)
{
  __shared__ __align__(16) char BUF[50176];
  const int tid  = threadIdx.x;
  const int lane = tid & 63;
  const int w    = tid >> 6;        // wave 0..3
  const int fr   = lane & 15;       // frag row
  const int fg   = lane >> 4;       // frag k-group / C row-group
  const long E0  = (long)blockIdx.x * 64;

  int*   e_s   = (int*)(BUF + OFF_E);
  int*   src_s = (int*)(BUF + OFF_SRC);
  int*   dst_s = (int*)(BUF + OFF_DST);
  float* sc_s  = (float*)(BUF + OFF_SC);

  // ---- phase 1: edge indices + scalar + sph pad (k>=10; k31 = 1.0 bias) ----
  if (tid < 64) {
    const int e = perm[E0 + tid];
    e_s[tid]   = e;
    src_s[tid] = ei[e];
    dst_s[tid] = ei[N_EDGES + e];
    sc_s[tid]  = sc_all[e];
  }
  for (int idx = tid; idx < 64 * 11; idx += 256) {
    const int i = idx / 11, ww = 5 + idx % 11;
    ((unsigned int*)(BUF + OFF_SPH))[i * 16 + ww] = (ww == 15) ? 0x3F800000u : 0u;
  }

  // ---- prologue: B1 fragments + bias scalars only (B2/B3 deferred) ----
  const s16x8* WFv = (const s16x8*)WF;
  s16x8 B1m[2], B1g[2];
#pragma unroll
  for (int q = 0; q < 2; ++q) { B1m[q] = WFv[(0 + q) * 256 + tid]; B1g[q] = WFv[(2 + q) * 256 + tid]; }
  const float b2j = b2v[16 * w + fr], g2j = g2v[16 * w + fr];
  const float b3j0 = b3v[16 * 2 * w + fr],       g3j0 = g3v[16 * 2 * w + fr];
  const float b3j1 = b3v[16 * (2 * w + 1) + fr], g3j1 = g3v[16 * (2 * w + 1) + fr];
  __syncthreads();   // bar A: e_s/src/dst/sc + sph pad visible

  // ---- phase 2a: eap loads into regs (issued FIRST) ----
  float sp[9];
  if (tid < 64) {
    const float* p = eap + (size_t)e_s[tid] * DSPH;
#pragma unroll
    for (int k = 0; k < 9; ++k) sp[k] = p[k];
  }

  // ---- phase 2b: hoisted T_A/T_B gathers (64 u32 loads, in flight) ----
  unsigned va_r[4][2][4], vb_r[4][2][4];
#pragma unroll
  for (int me = 0; me < 4; ++me)
#pragma unroll
    for (int q = 0; q < 2; ++q) {
      const int col = 16 * (2 * w + q) + fr;
#pragma unroll
      for (int r = 0; r < 4; ++r) {
        const int e = 16 * me + 4 * fg + r;
        va_r[me][q][r] = T_A[(size_t)src_s[e] * D + col];
        vb_r[me][q][r] = T_B[(size_t)dst_s[e] * D + col];
      }
    }

  // ---- phase 2c: B2 fragment loads (consumed at L2) ----
  s16x8 B2m[4], B2g[4];
#pragma unroll
  for (int ks = 0; ks < 4; ++ks) { B2m[ks] = WFv[(4 + ks) * 256 + tid]; B2g[ks] = WFv[(8 + ks) * 256 + tid]; }

  // ---- phase 2d: sph writes (waits only on eap loads) ----
  if (tid < 64) {
#pragma unroll
    for (int k = 0; k < 9; ++k)
      *(unsigned short*)(BUF + OFF_SPH + tid * 64 + k * 2) = f2b(sp[k]);
  }
  __syncthreads();   // bar B: sph visible

  // ---- L1: Z1 = sph @ W1cT(+bias) ----
  f32x4 a1m[4][2], a1g[4][2];
#pragma unroll
  for (int me = 0; me < 4; ++me)
#pragma unroll
    for (int q = 0; q < 2; ++q) { a1m[me][q] = (f32x4){0.f,0.f,0.f,0.f}; a1g[me][q] = (f32x4){0.f,0.f,0.f,0.f}; }
#pragma unroll
  for (int me = 0; me < 4; ++me) {
    const s16x8 a = *(const s16x8*)(BUF + OFF_SPH + (16 * me + fr) * 64 + fg * 16);
#pragma unroll
    for (int q = 0; q < 2; ++q) {
      a1m[me][q] = MFMA16(a, B1m[q], a1m[me][q]);
      a1g[me][q] = MFMA16(a, B1g[q], a1g[me][q]);
    }
  }
  // ---- L1 epi: add gathered pair-sums (already in regs), silu -> H1 ----
#pragma unroll
  for (int me = 0; me < 4; ++me)
#pragma unroll
    for (int q = 0; q < 2; ++q) {
      const int col = 16 * (2 * w + q) + fr;
#pragma unroll
      for (int r = 0; r < 4; ++r) {
        const int e = 16 * me + 4 * fg + r;
        const unsigned va = va_r[me][q][r];
        const unsigned vb = vb_r[me][q][r];
        const float zm = a1m[me][q][r] + blo(va) + blo(vb);
        const float zg = a1g[me][q][r] + bhi(va) + bhi(vb);
        const int cb = (col * 2) ^ ((e & 15) << 4);
        *(unsigned short*)(BUF + OFF_H1M + e * 256 + cb) = f2b(fsilu(zm));
        *(unsigned short*)(BUF + OFF_H1G + e * 256 + cb) = f2b(fsilu(zg));
      }
    }
  __syncthreads();   // bar C: H1 ready

  // ---- B3 fragment loads (consumed at L3) ----
  s16x8 B3m[2][2], B3g[2][2];
#pragma unroll
  for (int q = 0; q < 2; ++q)
#pragma unroll
    for (int ks = 0; ks < 2; ++ks) {
      B3m[q][ks] = WFv[(12 + 2 * q + ks) * 256 + tid];
      B3g[q][ks] = WFv[(16 + 2 * q + ks) * 256 + tid];
    }

  // ---- L2: Z2 = H1 @ W2 (+b2) ; silu -> H2 (Y region) ----
  f32x4 a2m[4], a2g[4];
#pragma unroll
  for (int me = 0; me < 4; ++me) { a2m[me] = (f32x4){b2j,b2j,b2j,b2j}; a2g[me] = (f32x4){g2j,g2j,g2j,g2j}; }
#pragma unroll
  for (int me = 0; me < 4; ++me) {
    const int row = 16 * me + fr;
#pragma unroll
    for (int ks = 0; ks < 4; ++ks) {
      const int cb = (64 * ks + 16 * fg) ^ ((row & 15) << 4);
      const s16x8 am = *(const s16x8*)(BUF + OFF_H1M + row * 256 + cb);
      const s16x8 ag = *(const s16x8*)(BUF + OFF_H1G + row * 256 + cb);
      a2m[me] = MFMA16(am, B2m[ks], a2m[me]);
      a2g[me] = MFMA16(ag, B2g[ks], a2g[me]);
    }
  }
  {
    const int j2 = 16 * w + fr;
#pragma unroll
    for (int me = 0; me < 4; ++me)
#pragma unroll
      for (int r = 0; r < 4; ++r) {
        const int e = 16 * me + 4 * fg + r;
        const int cb = (j2 * 2) ^ ((e & 7) << 4);
        *(unsigned short*)(BUF + OFF_H2M + e * 128 + cb) = f2b(fsilu(a2m[me][r]));
        *(unsigned short*)(BUF + OFF_H2G + e * 128 + cb) = f2b(fsilu(a2g[me][r]));
      }
  }
  __syncthreads();   // bar D: H2 ready (and all H1 reads done)

  // ---- L3: Z3 = H2 @ W3 (+b3) ; msg -> MSG (X region, overlays H1) ----
  f32x4 a3m[4][2], a3g[4][2];
#pragma unroll
  for (int me = 0; me < 4; ++me) {
    a3m[me][0] = (f32x4){b3j0,b3j0,b3j0,b3j0}; a3g[me][0] = (f32x4){g3j0,g3j0,g3j0,g3j0};
    a3m[me][1] = (f32x4){b3j1,b3j1,b3j1,b3j1}; a3g[me][1] = (f32x4){g3j1,g3j1,g3j1,g3j1};
  }
#pragma unroll
  for (int me = 0; me < 4; ++me) {
    const int row = 16 * me + fr;
#pragma unroll
    for (int ks = 0; ks < 2; ++ks) {
      const int cb = (64 * ks + 16 * fg) ^ ((row & 7) << 4);
      const s16x8 am = *(const s16x8*)(BUF + OFF_H2M + row * 128 + cb);
      const s16x8 ag = *(const s16x8*)(BUF + OFF_H2G + row * 128 + cb);
#pragma unroll
      for (int q = 0; q < 2; ++q) {
        a3m[me][q] = MFMA16(am, B3m[q][ks], a3m[me][q]);
        a3g[me][q] = MFMA16(ag, B3g[q][ks], a3g[me][q]);
      }
    }
  }
#pragma unroll
  for (int me = 0; me < 4; ++me)
#pragma unroll
    for (int q = 0; q < 2; ++q) {
      const int col = 16 * (2 * w + q) + fr;
#pragma unroll
      for (int r = 0; r < 4; ++r) {
        const int e = 16 * me + 4 * fg + r;
        const float msg = fsilu(a3m[me][q][r]) * fsig(a3g[me][q][r]) * sc_s[e];
        *(float*)(BUF + OFF_MSG + (e * 128 + col) * 4) = msg;
      }
    }
  __syncthreads();   // bar E: MSG ready

  // ---- segmented reduce: col-pair x edge-quarter (16-long chains) ----
  {
    const int cp = tid & 63;          // cols 2cp, 2cp+1
    const int qt = tid >> 6;          // quarter 0..3 (wave-uniform)
    const int base = 16 * qt;
    int cur = dst_s[base];
    float2 acc = *(const float2*)(BUF + OFF_MSG + (base * 128 + 2 * cp) * 4);
    for (int e2 = 1; e2 < 16; ++e2) {
      const int d = dst_s[base + e2];
      const float2 v = *(const float2*)(BUF + OFF_MSG + ((base + e2) * 128 + 2 * cp) * 4);
      if (d != cur) {
        atomicAdd(out + (size_t)cur * D + 2 * cp,     acc.x);
        atomicAdd(out + (size_t)cur * D + 2 * cp + 1, acc.y);
        cur = d; acc = v;
      } else { acc.x += v.x; acc.y += v.y; }
    }
    atomicAdd(out + (size_t)cur * D + 2 * cp,     acc.x);
    atomicAdd(out + (size_t)cur * D + 2 * cp + 1, acc.y);
  }
}

// ---------------------------------------------------------------------------
extern "C" void kernel_launch(void* const* d_in, const int* in_sizes, int n_in,
                              void* d_out, int out_size, void* d_ws, size_t ws_size,
                              hipStream_t stream) {
  const float* atom = (const float*)d_in[0];
  const float* ea   = (const float*)d_in[1];
  const float* eap  = (const float*)d_in[2];
  const int*   ei   = (const int*)d_in[3];
  const float* W1 = (const float*)d_in[5];
  const float* b1 = (const float*)d_in[6];
  const float* W2 = (const float*)d_in[7];
  const float* b2 = (const float*)d_in[8];
  const float* W3 = (const float*)d_in[9];
  const float* b3 = (const float*)d_in[10];
  const float* G1 = (const float*)d_in[11];
  const float* g1 = (const float*)d_in[12];
  const float* G2 = (const float*)d_in[13];
  const float* g2 = (const float*)d_in[14];
  const float* G3 = (const float*)d_in[15];
  const float* g3 = (const float*)d_in[16];
  const float* We = (const float*)d_in[17];
  const float* be = (const float*)d_in[18];
  float* out = (float*)d_out;

  char* wp = (char*)d_ws;
  unsigned* T_A = (unsigned*)wp;            wp += (size_t)N_ATOMS * D * 4;
  unsigned* T_B = (unsigned*)wp;            wp += (size_t)N_ATOMS * D * 4;
  int* counts = (int*)wp;                   wp += (size_t)N_ATOMS * 4;
  int* roff   = (int*)wp;                   wp += (size_t)(N_ATOMS + 4) * 4;
  int* cursor = (int*)wp;                   wp += (size_t)N_ATOMS * 4;
  int* perm   = (int*)wp;                   wp += (size_t)(N_EDGES + 64) * 4;
  ushort_t* WF  = (ushort_t*)wp;            wp += (size_t)20 * 256 * 8 * 2;
  ushort_t* WF2 = (ushort_t*)wp;            wp += (size_t)4 * 4 * 8 * 64 * 8 * 2;
  float* sc_all = (float*)wp;               wp += (size_t)N_EDGES * 4;

  hipMemsetAsync(counts, 0, (size_t)N_ATOMS * 4, stream);
  hipMemsetAsync(cursor, 0, (size_t)N_ATOMS * 4, stream);

  hipLaunchKernelGGL(k_wprepall, dim3(1), dim3(256), 0, stream,
                     W1, b1, W2, W3, G1, g1, G2, G3, WF, WF2);
  hipLaunchKernelGGL(k_sc_hist, dim3(N_EDGES / 32), dim3(256), 0, stream,
                     ea, We, be, ei, sc_all, counts);
  hipLaunchKernelGGL(k_scan, dim3(1), dim3(1024), 0, stream, counts, roff);
  hipLaunchKernelGGL(k_scatter, dim3((N_EDGES + 255) / 256), dim3(256), 0, stream,
                     ei, roff, cursor, perm);
  hipLaunchKernelGGL(k_tabmm, dim3((N_ATOMS + 63) / 64), dim3(256), 0, stream,
                     atom, WF2, T_A, T_B, out);
  hipLaunchKernelGGL(k_tile, dim3(N_EDGES / 64), dim3(256), 0, stream,
                     eap, ei, perm, T_A, T_B, WF, b2, g2, b3, g3, sc_all, out);
}